// Round 3
// baseline (5498.590 us; speedup 1.0000x reference)
//
#include <hip/hip_runtime.h>

// LSTM_27152783245909 — persistent-recurrence LSTM for MI355X (gfx950)
// R6: hardened XCD relay (R5 hung; suspect sc0-only polling not L1-bypassing
// and/or rocprof dispatch-replay with stale election counters -> no relay ->
// infinite rdy spin). Changes vs R5:
//  * ready-word REMOVED. Consumers poll the relay's republished slice (rsl)
//    directly with the per-short bit14 tag check -- tags are the ground
//    truth, self-cleaning against poison (0xFF = tag1 != first-expected 0)
//    and against t+-2 occupants (opposite tags by construction).
//  * L2 poll is BOUNDED (96 rounds) -> falls back to the R4 direct-MALL
//    poll (hardware-proven, unbounded, self-cleaning). 3 consecutive
//    fallbacks -> sticky MALL mode. No wait in the kernel can hang even if
//    sc0 loads never observe the relay's L2 stores or no relay exists.
//  * relay: poll MALL -> republish verbatim (plain stores -> own-XCD L2) ->
//    continue. No barrier, no flag. Duplicate relays are benign (identical
//    verbatim bytes); zero relays only cost speed (fallback), never liveness.

#define T_ 256

typedef __attribute__((ext_vector_type(8))) short bf16x8;
typedef __attribute__((ext_vector_type(4))) float floatx4;
typedef __attribute__((ext_vector_type(4))) int intx4;

__device__ __forceinline__ unsigned short f2bf(float f) {
  unsigned u = __builtin_bit_cast(unsigned, f);
  u += 0x7FFFu + ((u >> 16) & 1u);   // round-nearest-even
  return (unsigned short)(u >> 16);
}

__device__ __forceinline__ float sigm(float x) { return 1.0f / (1.0f + __expf(-x)); }

// ---------------- W_out fp32 -> bf16 (512x1024) ----------------
__global__ void cvt_w(const float* __restrict__ w, unsigned short* __restrict__ o) {
  const size_t g = (size_t)blockIdx.x * 256 + threadIdx.x;
  const float* s = w + g * 8;
  bf16x8 v;
#pragma unroll
  for (int i = 0; i < 8; ++i) v[i] = (short)f2bf(s[i]);
  *(bf16x8*)(o + g * 8) = v;
}

// ---------------- x[B=64, I=512, T=256] fp32 -> xT[T,B,I] bf16 ----------------
__global__ void transpose_x(const float* __restrict__ x, unsigned short* __restrict__ xT) {
  __shared__ float tile[32][33];
  const int b = blockIdx.z, i0 = blockIdx.y * 32, t0 = blockIdx.x * 32;
  const int tx = threadIdx.x & 31, ty = threadIdx.x >> 5;
#pragma unroll
  for (int p = 0; p < 4; ++p) {
    const int i = ty + p * 8;
    tile[i][tx] = x[((size_t)b * 512 + i0 + i) * 256 + t0 + tx];
  }
  __syncthreads();
#pragma unroll
  for (int p = 0; p < 4; ++p) {
    const int t = ty + p * 8;
    xT[((size_t)(t0 + t) * 64 + b) * 512 + i0 + tx] = f2bf(tile[tx][t]);
  }
}

// ---------------- persistent recurrence ----------------
__global__ __launch_bounds__(512, 1) void lstm_rec(
    const float* __restrict__ Whh, const float* __restrict__ Wih,
    const float* __restrict__ bih, const float* __restrict__ bhh,
    const float* __restrict__ h0, const float* __restrict__ c0,
    const unsigned short* __restrict__ xT,
    unsigned short* __restrict__ hbuf,   // [2][64][1024] bf16 (MALL, sc0/sc1 only)
    unsigned short* __restrict__ rbuf,   // [2][8][4][16][1024] bf16 (XCD-local L2)
    unsigned* __restrict__ ctrl,         // [32] election counters
    unsigned short* __restrict__ call)   // [256][64][1024] bf16 (normal cached)
{
  const int tid = threadIdx.x;
  const int lane = tid & 63;
  const int wv = tid >> 6;           // 0..7
  const int nh = wv & 1, kq = wv >> 1;
  const int mg = blockIdx.x & 3, ng = blockIdx.x >> 2;
  const int l15 = lane & 15, lq = lane >> 4;
  const int row = mg * 16 + l15;     // A-fragment batch row (x-part)

  unsigned xcc;
  asm volatile("s_getreg_b32 %0, hwreg(HW_REG_XCC_ID)" : "=s"(xcc));
  xcc &= 7u;

  __shared__ unsigned short hlds[16 * 1032];      // 16 rows, stride 1032 (+8 pad)
  __shared__ float gpart[4][16][66];              // [kq][m][gate*16+j]
  __shared__ int s_isrelay;

  // ---- relay election: first arrival per (physical xcd, mg) wins.
  // Duplicate winners impossible (atomic); zero winners (stale counters in a
  // dispatch-replay) is survivable -- consumers fall back to MALL.
  if (tid == 0) {
    unsigned old = __hip_atomic_fetch_add(ctrl + (xcc * 4 + mg), 1u,
                                          __ATOMIC_RELAXED, __HIP_MEMORY_SCOPE_SYSTEM);
    s_isrelay = (old == 0u);
  }

  // persistent B fragments: 2 gates x 12 ksteps = 96 VGPRs/lane
  bf16x8 bfrag[2][12];
#pragma unroll
  for (int nt = 0; nt < 2; ++nt) {
    const int ncol = (2 * nh + nt) * 1024 + ng * 16 + l15;
#pragma unroll
    for (int ks = 0; ks < 12; ++ks) {
      const int kg = kq * 384 + ks * 32 + lq * 8;   // never straddles 1024
      const float* s = (kg < 1024) ? (Whh + (size_t)ncol * 1024 + kg)
                                   : (Wih + (size_t)ncol * 512 + (kg - 1024));
      bf16x8 v;
#pragma unroll
      for (int i = 0; i < 8; ++i) v[i] = (short)f2bf(s[i]);
      bfrag[nt][ks] = v;
    }
  }

  // per-thread state (waves 0..3): one (batch m, unit j) cell each
  const int m_loc = tid >> 4, j = tid & 15;
  const int row_g = mg * 16 + m_loc;
  const int unit = ng * 16 + j;
  float c_reg = 0.f, bs0 = 0.f, bs1 = 0.f, bs2 = 0.f, bs3 = 0.f;
  if (tid < 256) {
    c_reg = c0[unit];
    bs0 = bih[unit] + bhh[unit];
    bs1 = bih[1024 + unit] + bhh[1024 + unit];
    bs2 = bih[2048 + unit] + bhh[2048 + unit];
    bs3 = bih[3072 + unit] + bhh[3072 + unit];
  }
  __syncthreads();
  const bool is_relay = (s_isrelay != 0);

  int fb_streak = 0;          // consecutive steps that needed MALL fallback
  bool sticky_mall = false;   // after 3: stop trying the L2 fast path

  for (int t = 0; t < T_; ++t) {
    intx4 av0, av1, av2, av3;
    const unsigned tagpat = (((t - 1) >> 1) & 1) ? 0x40004000u : 0u;
    unsigned short* const rsl =
        rbuf + ((size_t)(((t + 1) & 1) * 32 + xcc * 4 + mg)) * 16384;

    // ---- relay: pull h_{t-1} slice from MALL, republish into own-XCD L2 ----
    if (t > 0 && is_relay) {
      const unsigned short* gsrc = hbuf + ((t + 1) & 1) * 65536
                                 + (size_t)(mg * 16) * 1024 + (size_t)tid * 8;
      while (true) {
        asm volatile(
            "global_load_dwordx4 %0, %4, off sc0 sc1\n\t"
            "global_load_dwordx4 %1, %5, off sc0 sc1\n\t"
            "global_load_dwordx4 %2, %6, off sc0 sc1\n\t"
            "global_load_dwordx4 %3, %7, off sc0 sc1\n\t"
            "s_waitcnt vmcnt(0)"
            : "=v"(av0), "=v"(av1), "=v"(av2), "=v"(av3)
            : "v"(gsrc), "v"(gsrc + 4096), "v"(gsrc + 8192), "v"(gsrc + 12288)
            : "memory");
        unsigned bad = 0;
#pragma unroll
        for (int d = 0; d < 4; ++d) {
          bad |= ((unsigned)av0[d] ^ tagpat) & 0x40004000u;
          bad |= ((unsigned)av1[d] ^ tagpat) & 0x40004000u;
          bad |= ((unsigned)av2[d] ^ tagpat) & 0x40004000u;
          bad |= ((unsigned)av3[d] ^ tagpat) & 0x40004000u;
        }
        if (!bad) break;
      }
      // republish verbatim (tags intact) -> this XCD's L2 (plain stores).
      // No drain/barrier needed: consumers verify per-granule tags.
      unsigned short* rdst = rsl + (size_t)tid * 8;
      *(intx4*)(rdst)         = av0;
      *(intx4*)(rdst + 4096)  = av1;
      *(intx4*)(rdst + 8192)  = av2;
      *(intx4*)(rdst + 12288) = av3;
    }

    // ---- x-part MFMA (independent of h_{t-1}; overlaps producers/relay) ----
    const unsigned short* bx = xT + ((size_t)t * 64 + row) * 512;
    floatx4 zero = {0.f, 0.f, 0.f, 0.f};
    floatx4 acc0 = zero, acc1 = zero;
#pragma unroll
    for (int ks = 0; ks < 12; ++ks) {
      const int kg = kq * 384 + ks * 32 + lq * 8;
      if (kg >= 1024) {
        const bf16x8 af = *(const bf16x8*)(bx + (kg - 1024));
        acc0 = __builtin_amdgcn_mfma_f32_16x16x32_bf16(af, bfrag[0][ks], acc0, 0, 0, 0);
        acc1 = __builtin_amdgcn_mfma_f32_16x16x32_bf16(af, bfrag[1][ks], acc1, 0, 0, 0);
      }
    }

    // ---- obtain h_{t-1} rows [16mg,16mg+16) -> LDS ----
    if (t == 0) {
      // h_{-1} = h0 broadcast (N(0,1): must bypass the tag path)
#pragma unroll
      for (int p = 0; p < 4; ++p) {
        const int e = tid + p * 512;
        const int r = e >> 7, col = (e & 127) * 8;
        const float* s = h0 + col;
        bf16x8 v;
#pragma unroll
        for (int i = 0; i < 8; ++i) v[i] = (short)f2bf(s[i]);
        *(bf16x8*)(hlds + r * 1032 + col) = v;
      }
    } else {
      if (!is_relay) {
        bool got = false;
        if (!sticky_mall) {
          // fast path: poll own-XCD republished slice (sc0, L2-served if the
          // hardware honors it; tags prove freshness either way).
          const unsigned short* gsrc = rsl + (size_t)tid * 8;
          for (int round = 0; round < 96; ++round) {
            asm volatile(
                "global_load_dwordx4 %0, %4, off sc0\n\t"
                "global_load_dwordx4 %1, %5, off sc0\n\t"
                "global_load_dwordx4 %2, %6, off sc0\n\t"
                "global_load_dwordx4 %3, %7, off sc0\n\t"
                "s_waitcnt vmcnt(0)"
                : "=v"(av0), "=v"(av1), "=v"(av2), "=v"(av3)
                : "v"(gsrc), "v"(gsrc + 4096), "v"(gsrc + 8192), "v"(gsrc + 12288)
                : "memory");
            unsigned bad = 0;
#pragma unroll
            for (int d = 0; d < 4; ++d) {
              bad |= ((unsigned)av0[d] ^ tagpat) & 0x40004000u;
              bad |= ((unsigned)av1[d] ^ tagpat) & 0x40004000u;
              bad |= ((unsigned)av2[d] ^ tagpat) & 0x40004000u;
              bad |= ((unsigned)av3[d] ^ tagpat) & 0x40004000u;
            }
            if (!bad) { got = true; break; }
            __builtin_amdgcn_s_sleep(1);
          }
        }
        if (got) {
          fb_streak = 0;
        } else {
          // fallback: direct MALL poll (R4 path, hardware-proven, unbounded,
          // self-cleaning tags). Guarantees liveness in every state.
          if (++fb_streak >= 3) sticky_mall = true;
          const unsigned short* gsrc = hbuf + ((t + 1) & 1) * 65536
                                     + (size_t)(mg * 16) * 1024 + (size_t)tid * 8;
          while (true) {
            asm volatile(
                "global_load_dwordx4 %0, %4, off sc0 sc1\n\t"
                "global_load_dwordx4 %1, %5, off sc0 sc1\n\t"
                "global_load_dwordx4 %2, %6, off sc0 sc1\n\t"
                "global_load_dwordx4 %3, %7, off sc0 sc1\n\t"
                "s_waitcnt vmcnt(0)"
                : "=v"(av0), "=v"(av1), "=v"(av2), "=v"(av3)
                : "v"(gsrc), "v"(gsrc + 4096), "v"(gsrc + 8192), "v"(gsrc + 12288)
                : "memory");
            unsigned bad = 0;
#pragma unroll
            for (int d = 0; d < 4; ++d) {
              bad |= ((unsigned)av0[d] ^ tagpat) & 0x40004000u;
              bad |= ((unsigned)av1[d] ^ tagpat) & 0x40004000u;
              bad |= ((unsigned)av2[d] ^ tagpat) & 0x40004000u;
              bad |= ((unsigned)av3[d] ^ tagpat) & 0x40004000u;
            }
            if (!bad) break;
          }
        }
      }
      intx4 avv[4] = {av0, av1, av2, av3};
#pragma unroll
      for (int p = 0; p < 4; ++p) {
        intx4 v = avv[p];
#pragma unroll
        for (int d = 0; d < 4; ++d) v[d] &= (int)0xBFFFBFFFu;   // strip tag bit
        const int e = tid + p * 512;
        const int r = e >> 7, col = (e & 127) * 8;
        *(intx4*)(hlds + r * 1032 + col) = v;
      }
    }
    __syncthreads();

    // ---- h-part MFMAs from LDS ----
#pragma unroll
    for (int ks = 0; ks < 12; ++ks) {
      const int kg = kq * 384 + ks * 32 + lq * 8;
      if (kg < 1024) {
        const bf16x8 af = *(const bf16x8*)(hlds + l15 * 1032 + kg);
        acc0 = __builtin_amdgcn_mfma_f32_16x16x32_bf16(af, bfrag[0][ks], acc0, 0, 0, 0);
        acc1 = __builtin_amdgcn_mfma_f32_16x16x32_bf16(af, bfrag[1][ks], acc1, 0, 0, 0);
      }
    }

    // C layout: col = lane&15, row = (lane>>4)*4 + r
#pragma unroll
    for (int r = 0; r < 4; ++r) {
      gpart[kq][lq * 4 + r][(2 * nh) * 16 + l15]     = acc0[r];
      gpart[kq][lq * 4 + r][(2 * nh + 1) * 16 + l15] = acc1[r];
    }
    __syncthreads();

    if (tid < 256) {
      float gi = bs0, gf = bs1, gg = bs2, go = bs3;
#pragma unroll
      for (int q = 0; q < 4; ++q) {
        gi += gpart[q][m_loc][j];
        gf += gpart[q][m_loc][16 + j];
        gg += gpart[q][m_loc][32 + j];
        go += gpart[q][m_loc][48 + j];
      }
      const float iv = sigm(gi), fv = sigm(gf), gv = tanhf(gg), ov = sigm(go);
      c_reg = fv * c_reg + iv * gv;
      const float hv = ov * tanhf(c_reg);
      // publish h first (critical path), tagged in bit14 (|hv| < 1)
      unsigned short* hp = hbuf + (t & 1) * 65536 + row_g * 1024 + unit;
      const unsigned hb = (unsigned)f2bf(hv) | ((unsigned)((t >> 1) & 1) << 14);
      asm volatile("global_store_short %0, %1, off sc0 sc1"
                   :: "v"(hp), "v"(hb) : "memory");
      call[((size_t)t * 64 + row_g) * 1024 + unit] = f2bf(c_reg);
    }
  }
}

// ---------------- output head: logits + softmax, fully parallel over t ----------------
__global__ __launch_bounds__(256, 1) void lstm_head(
    const unsigned short* __restrict__ call,
    const unsigned short* __restrict__ wout,
    const float* __restrict__ bout,
    float* __restrict__ out)
{
  const int tb = blockIdx.x;
  const int lane = threadIdx.x & 63;
  const int wv = threadIdx.x >> 6;
  const int l15 = lane & 15, lq = lane >> 4;

  __shared__ float sred[2][4][64];

  floatx4 zero = {0.f, 0.f, 0.f, 0.f};
  floatx4 acc[4][8];
#pragma unroll
  for (int mt = 0; mt < 4; ++mt)
#pragma unroll
    for (int nt = 0; nt < 8; ++nt) acc[mt][nt] = zero;

  const unsigned short* abase = call + ((size_t)tb * 64 + l15) * 1024 + lq * 8;
  const unsigned short* bbase = wout + ((size_t)(wv * 128 + l15)) * 1024 + lq * 8;

#pragma unroll 2
  for (int ks = 0; ks < 32; ++ks) {
    bf16x8 a[4];
#pragma unroll
    for (int mt = 0; mt < 4; ++mt)
      a[mt] = *(const bf16x8*)(abase + (size_t)mt * 16 * 1024 + ks * 32);
#pragma unroll
    for (int nt = 0; nt < 8; ++nt) {
      const bf16x8 b = *(const bf16x8*)(bbase + (size_t)nt * 16 * 1024 + ks * 32);
#pragma unroll
      for (int mt = 0; mt < 4; ++mt)
        acc[mt][nt] = __builtin_amdgcn_mfma_f32_16x16x32_bf16(a[mt], b, acc[mt][nt], 0, 0, 0);
    }
  }

#pragma unroll
  for (int nt = 0; nt < 8; ++nt) {
    const float bo = bout[wv * 128 + nt * 16 + l15];
#pragma unroll
    for (int mt = 0; mt < 4; ++mt)
#pragma unroll
      for (int r = 0; r < 4; ++r) acc[mt][nt][r] += bo;
  }

  float rmax[4][4];
#pragma unroll
  for (int mt = 0; mt < 4; ++mt)
#pragma unroll
    for (int r = 0; r < 4; ++r) {
      float m = acc[mt][0][r];
#pragma unroll
      for (int nt = 1; nt < 8; ++nt) m = fmaxf(m, acc[mt][nt][r]);
      m = fmaxf(m, __shfl_xor(m, 1, 64));
      m = fmaxf(m, __shfl_xor(m, 2, 64));
      m = fmaxf(m, __shfl_xor(m, 4, 64));
      m = fmaxf(m, __shfl_xor(m, 8, 64));
      rmax[mt][r] = m;
    }
  if (l15 == 0) {
#pragma unroll
    for (int mt = 0; mt < 4; ++mt)
#pragma unroll
      for (int r = 0; r < 4; ++r) sred[0][wv][mt * 16 + lq * 4 + r] = rmax[mt][r];
  }
  __syncthreads();
  float gmax[4][4], rsum[4][4];
#pragma unroll
  for (int mt = 0; mt < 4; ++mt)
#pragma unroll
    for (int r = 0; r < 4; ++r) {
      const int rw = mt * 16 + lq * 4 + r;
      gmax[mt][r] = fmaxf(fmaxf(sred[0][0][rw], sred[0][1][rw]),
                          fmaxf(sred[0][2][rw], sred[0][3][rw]));
      rsum[mt][r] = 0.f;
    }
#pragma unroll
  for (int mt = 0; mt < 4; ++mt)
#pragma unroll
    for (int nt = 0; nt < 8; ++nt)
#pragma unroll
      for (int r = 0; r < 4; ++r) {
        const float e = __expf(acc[mt][nt][r] - gmax[mt][r]);
        acc[mt][nt][r] = e;
        rsum[mt][r] += e;
      }
#pragma unroll
  for (int mt = 0; mt < 4; ++mt)
#pragma unroll
    for (int r = 0; r < 4; ++r) {
      float s = rsum[mt][r];
      s += __shfl_xor(s, 1, 64);
      s += __shfl_xor(s, 2, 64);
      s += __shfl_xor(s, 4, 64);
      s += __shfl_xor(s, 8, 64);
      rsum[mt][r] = s;
    }
  if (l15 == 0) {
#pragma unroll
    for (int mt = 0; mt < 4; ++mt)
#pragma unroll
      for (int r = 0; r < 4; ++r) sred[1][wv][mt * 16 + lq * 4 + r] = rsum[mt][r];
  }
  __syncthreads();
#pragma unroll
  for (int mt = 0; mt < 4; ++mt)
#pragma unroll
    for (int r = 0; r < 4; ++r) {
      const int rw = mt * 16 + lq * 4 + r;
      const float inv = 1.0f / (sred[1][0][rw] + sred[1][1][rw] +
                                sred[1][2][rw] + sred[1][3][rw]);
      float* orow = out + ((size_t)tb * 64 + rw) * 512 + wv * 128 + l15;
#pragma unroll
      for (int nt = 0; nt < 8; ++nt) orow[nt * 16] = acc[mt][nt][r] * inv;
    }
}

// ---------------- launch ----------------
extern "C" void kernel_launch(void* const* d_in, const int* in_sizes, int n_in,
                              void* d_out, int out_size, void* d_ws, size_t ws_size,
                              hipStream_t stream) {
  const float* x    = (const float*)d_in[0];
  const float* Wih  = (const float*)d_in[1];
  const float* Whh  = (const float*)d_in[2];
  const float* bih  = (const float*)d_in[3];
  const float* bhh  = (const float*)d_in[4];
  const float* Wout = (const float*)d_in[5];
  const float* bout = (const float*)d_in[6];
  const float* h0   = (const float*)d_in[7];
  const float* c0   = (const float*)d_in[8];
  float* out = (float*)d_out;

  char* ws = (char*)d_ws;
  unsigned* ctrl        = (unsigned*)(ws + 0);                  //   8 KB (election)
  unsigned short* hbuf  = (unsigned short*)(ws + 8192);         // 256 KB
  unsigned short* rbuf  = (unsigned short*)(ws + 270336);       //   2 MB
  unsigned short* woutb = (unsigned short*)(ws + 2367488);      //   1 MB
  unsigned short* xT    = (unsigned short*)(ws + 3416064);      //  16 MB
  unsigned short* call  = (unsigned short*)(ws + 20193280);     //  32 MB

  hipMemsetAsync(ctrl, 0, 8192, stream);        // election counters
  hipMemsetAsync(hbuf, 0xFF, 262144, stream);   // poison: bit14=1 != tag 0
  hipMemsetAsync(rbuf, 0xFF, 2097152, stream);
  cvt_w<<<256, 256, 0, stream>>>(Wout, woutb);
  transpose_x<<<dim3(8, 16, 64), 256, 0, stream>>>(x, xT);
  lstm_rec<<<256, 512, 0, stream>>>(Whh, Wih, bih, bhh, h0, c0, xT, hbuf, rbuf, ctrl, call);
  lstm_head<<<256, 256, 0, stream>>>(call, woutb, bout, out);
}

// Round 4
// 1314.106 us; speedup vs baseline: 4.1843x; 4.1843x over previous
//
#include <hip/hip_runtime.h>

// LSTM_27152783245909 — persistent-recurrence LSTM for MI355X (gfx950)
// R7: back to the PROVEN R4 protocol (direct MALL exchange, bit14 tags,
// sc0 sc1 only — R6's L2 relay was 5.5x worse: sc0-only reads appear to be
// served from stale L1 until self-eviction). Three surgical fixes inside the
// R4 protocol:
//  1. packed publish: shuffle-pack 256 tagged shorts -> 32 dwordx4 sc0/sc1
//     stores per block (8x fewer MALL write transactions, faster landing).
//  2. sample-first poll: spin on granule 0 only (16B/thread, 8KB/block/round;
//     rows 0-3 sample all 64 producers), then verified read of the rest.
//  3. final read skips the sample granule (tag-pass = final data; single
//     writer, write-once per slot): 24KB instead of 32KB.
// All waits are unbounded tag-verified MALL polls: self-cleaning vs poison
// (0xFF = tag1 != first expected 0) and vs t+-2 slot occupants (opposite
// tags by construction). No flags, no fences, no relay.

#define T_ 256

typedef __attribute__((ext_vector_type(8))) short bf16x8;
typedef __attribute__((ext_vector_type(4))) float floatx4;
typedef __attribute__((ext_vector_type(4))) int intx4;

__device__ __forceinline__ unsigned short f2bf(float f) {
  unsigned u = __builtin_bit_cast(unsigned, f);
  u += 0x7FFFu + ((u >> 16) & 1u);   // round-nearest-even
  return (unsigned short)(u >> 16);
}

__device__ __forceinline__ float sigm(float x) { return 1.0f / (1.0f + __expf(-x)); }

// ---------------- W_out fp32 -> bf16 (512x1024) ----------------
__global__ void cvt_w(const float* __restrict__ w, unsigned short* __restrict__ o) {
  const size_t g = (size_t)blockIdx.x * 256 + threadIdx.x;
  const float* s = w + g * 8;
  bf16x8 v;
#pragma unroll
  for (int i = 0; i < 8; ++i) v[i] = (short)f2bf(s[i]);
  *(bf16x8*)(o + g * 8) = v;
}

// ---------------- x[B=64, I=512, T=256] fp32 -> xT[T,B,I] bf16 ----------------
__global__ void transpose_x(const float* __restrict__ x, unsigned short* __restrict__ xT) {
  __shared__ float tile[32][33];
  const int b = blockIdx.z, i0 = blockIdx.y * 32, t0 = blockIdx.x * 32;
  const int tx = threadIdx.x & 31, ty = threadIdx.x >> 5;
#pragma unroll
  for (int p = 0; p < 4; ++p) {
    const int i = ty + p * 8;
    tile[i][tx] = x[((size_t)b * 512 + i0 + i) * 256 + t0 + tx];
  }
  __syncthreads();
#pragma unroll
  for (int p = 0; p < 4; ++p) {
    const int t = ty + p * 8;
    xT[((size_t)(t0 + t) * 64 + b) * 512 + i0 + tx] = f2bf(tile[tx][t]);
  }
}

// ---------------- persistent recurrence ----------------
// 256 blocks x 512 thr, 1 block/CU. Block (mg,ng): batch rows [16mg,16mg+16),
// hidden units [16ng,16ng+16). Wave (nh = gate pair, kq = K quarter of 1536).
__global__ __launch_bounds__(512, 1) void lstm_rec(
    const float* __restrict__ Whh, const float* __restrict__ Wih,
    const float* __restrict__ bih, const float* __restrict__ bhh,
    const float* __restrict__ h0, const float* __restrict__ c0,
    const unsigned short* __restrict__ xT,
    unsigned short* __restrict__ hbuf,   // [2][64][1024] bf16 (MALL, sc0/sc1 only)
    unsigned short* __restrict__ call)   // [256][64][1024] bf16 (normal cached)
{
  const int tid = threadIdx.x;
  const int lane = tid & 63;
  const int wv = tid >> 6;           // 0..7
  const int nh = wv & 1, kq = wv >> 1;
  const int mg = blockIdx.x & 3, ng = blockIdx.x >> 2;
  const int l15 = lane & 15, lq = lane >> 4;
  const int row = mg * 16 + l15;     // A-fragment batch row (x-part)

  __shared__ unsigned short hlds[16 * 1032];      // 16 rows, stride 1032 (+8 pad)
  __shared__ float gpart[4][16][66];              // [kq][m][gate*16+j]

  // persistent B fragments: 2 gates x 12 ksteps = 96 VGPRs/lane
  bf16x8 bfrag[2][12];
#pragma unroll
  for (int nt = 0; nt < 2; ++nt) {
    const int ncol = (2 * nh + nt) * 1024 + ng * 16 + l15;
#pragma unroll
    for (int ks = 0; ks < 12; ++ks) {
      const int kg = kq * 384 + ks * 32 + lq * 8;   // never straddles 1024
      const float* s = (kg < 1024) ? (Whh + (size_t)ncol * 1024 + kg)
                                   : (Wih + (size_t)ncol * 512 + (kg - 1024));
      bf16x8 v;
#pragma unroll
      for (int i = 0; i < 8; ++i) v[i] = (short)f2bf(s[i]);
      bfrag[nt][ks] = v;
    }
  }

  // per-thread state (waves 0..3): one (batch m, unit j) cell each
  const int m_loc = tid >> 4, j = tid & 15;
  const int row_g = mg * 16 + m_loc;
  const int unit = ng * 16 + j;
  float c_reg = 0.f, bs0 = 0.f, bs1 = 0.f, bs2 = 0.f, bs3 = 0.f;
  if (tid < 256) {
    c_reg = c0[unit];
    bs0 = bih[unit] + bhh[unit];
    bs1 = bih[1024 + unit] + bhh[1024 + unit];
    bs2 = bih[2048 + unit] + bhh[2048 + unit];
    bs3 = bih[3072 + unit] + bhh[3072 + unit];
  }

  for (int t = 0; t < T_; ++t) {
    const unsigned short* bx = xT + ((size_t)t * 64 + row) * 512;
    floatx4 zero = {0.f, 0.f, 0.f, 0.f};
    floatx4 acc0 = zero, acc1 = zero;

    // ---- x-part (no dependence on h_{t-1}; overlaps peers' h stores) ----
#pragma unroll
    for (int ks = 0; ks < 12; ++ks) {
      const int kg = kq * 384 + ks * 32 + lq * 8;
      if (kg >= 1024) {
        const bf16x8 af = *(const bf16x8*)(bx + (kg - 1024));
        acc0 = __builtin_amdgcn_mfma_f32_16x16x32_bf16(af, bfrag[0][ks], acc0, 0, 0, 0);
        acc1 = __builtin_amdgcn_mfma_f32_16x16x32_bf16(af, bfrag[1][ks], acc1, 0, 0, 0);
      }
    }

    // ---- obtain h_{t-1} rows [16mg,16mg+16) -> LDS ----
    if (t == 0) {
      // h_{-1} = h0 broadcast over batch (N(0,1): bypasses the tag path)
#pragma unroll
      for (int p = 0; p < 4; ++p) {
        const int e = tid + p * 512;
        const int r = e >> 7, col = (e & 127) * 8;
        const float* s = h0 + col;
        bf16x8 v;
#pragma unroll
        for (int i = 0; i < 8; ++i) v[i] = (short)f2bf(s[i]);
        *(bf16x8*)(hlds + r * 1032 + col) = v;
      }
    } else {
      const unsigned short* hprev = hbuf + ((t + 1) & 1) * 65536;
      const unsigned short* gsrc = hprev + (size_t)(mg * 16) * 1024 + (size_t)tid * 8;
      const unsigned tagpat = (((t - 1) >> 1) & 1) ? 0x40004000u : 0u;
      intx4 a0, a1, a2, a3;
      // -- sample poll: granule 0 only (rows 0-3 contain 4 rows from every
      //    one of the 64 producers). 16B/thread/round.
      while (true) {
        asm volatile("global_load_dwordx4 %0, %1, off sc0 sc1\n\ts_waitcnt vmcnt(0)"
                     : "=v"(a0) : "v"(gsrc) : "memory");
        unsigned bad = 0;
#pragma unroll
        for (int d = 0; d < 4; ++d) bad |= ((unsigned)a0[d] ^ tagpat) & 0x40004000u;
        if (!bad) break;
      }
      // -- verified read of the remaining granules (usually one pass).
      //    Granule 0 is final (tag-pass, single write-once writer): keep it.
      while (true) {
        asm volatile(
            "global_load_dwordx4 %0, %3, off sc0 sc1\n\t"
            "global_load_dwordx4 %1, %4, off sc0 sc1\n\t"
            "global_load_dwordx4 %2, %5, off sc0 sc1\n\t"
            "s_waitcnt vmcnt(0)"
            : "=v"(a1), "=v"(a2), "=v"(a3)
            : "v"(gsrc + 4096), "v"(gsrc + 8192), "v"(gsrc + 12288)
            : "memory");
        unsigned bad = 0;
#pragma unroll
        for (int d = 0; d < 4; ++d) {
          bad |= ((unsigned)a1[d] ^ tagpat) & 0x40004000u;
          bad |= ((unsigned)a2[d] ^ tagpat) & 0x40004000u;
          bad |= ((unsigned)a3[d] ^ tagpat) & 0x40004000u;
        }
        if (!bad) break;
      }
      intx4 av[4] = {a0, a1, a2, a3};
#pragma unroll
      for (int p = 0; p < 4; ++p) {
        intx4 v = av[p];
#pragma unroll
        for (int d = 0; d < 4; ++d) v[d] &= (int)0xBFFFBFFFu;   // strip tag bit
        const int e = tid + p * 512;
        const int r = e >> 7, col = (e & 127) * 8;
        *(intx4*)(hlds + r * 1032 + col) = v;
      }
    }
    __syncthreads();

    // ---- h-part MFMAs from LDS ----
#pragma unroll
    for (int ks = 0; ks < 12; ++ks) {
      const int kg = kq * 384 + ks * 32 + lq * 8;
      if (kg < 1024) {
        const bf16x8 af = *(const bf16x8*)(hlds + l15 * 1032 + kg);
        acc0 = __builtin_amdgcn_mfma_f32_16x16x32_bf16(af, bfrag[0][ks], acc0, 0, 0, 0);
        acc1 = __builtin_amdgcn_mfma_f32_16x16x32_bf16(af, bfrag[1][ks], acc1, 0, 0, 0);
      }
    }

    // C layout: col = lane&15, row = (lane>>4)*4 + r
#pragma unroll
    for (int r = 0; r < 4; ++r) {
      gpart[kq][lq * 4 + r][(2 * nh) * 16 + l15]     = acc0[r];
      gpart[kq][lq * 4 + r][(2 * nh + 1) * 16 + l15] = acc1[r];
    }
    __syncthreads();

    if (tid < 256) {
      float gi = bs0, gf = bs1, gg = bs2, go = bs3;
#pragma unroll
      for (int q = 0; q < 4; ++q) {
        gi += gpart[q][m_loc][j];
        gf += gpart[q][m_loc][16 + j];
        gg += gpart[q][m_loc][32 + j];
        go += gpart[q][m_loc][48 + j];
      }
      const float iv = sigm(gi), fv = sigm(gf), gv = tanhf(gg), ov = sigm(go);
      c_reg = fv * c_reg + iv * gv;
      const float hv = ov * tanhf(c_reg);

      // ---- packed publish: 8 lanes' tagged shorts -> one dwordx4 store ----
      // |hv| < 1 so bit14 of f2bf(hv) is always 0; tag = (t>>1)&1.
      const unsigned hb = (unsigned)f2bf(hv) | ((unsigned)((t >> 1) & 1) << 14);
      const int base = lane & 56;               // 8-lane group (same row, j&~7)
      intx4 pk;
#pragma unroll
      for (int k = 0; k < 4; ++k) {
        const unsigned lo = (unsigned)__shfl((int)hb, base + 2 * k, 64) & 0xFFFFu;
        const unsigned hi = (unsigned)__shfl((int)hb, base + 2 * k + 1, 64);
        pk[k] = (int)(lo | (hi << 16));
      }
      if ((tid & 7) == 0) {
        unsigned short* hp = hbuf + (t & 1) * 65536 + row_g * 1024 + (unit & ~7);
        asm volatile("global_store_dwordx4 %0, %1, off sc0 sc1"
                     :: "v"(hp), "v"(pk) : "memory");
      }
      call[((size_t)t * 64 + row_g) * 1024 + unit] = f2bf(c_reg);
    }
    // 2 barriers/step: hlds-fill barrier + gpart barrier. Next iteration's
    // hlds write is safe (all threads passed the gpart barrier, which
    // post-dates all hlds reads).
  }
}

// ---------------- output head: logits + softmax, fully parallel over t ----------------
__global__ __launch_bounds__(256, 1) void lstm_head(
    const unsigned short* __restrict__ call,
    const unsigned short* __restrict__ wout,
    const float* __restrict__ bout,
    float* __restrict__ out)
{
  const int tb = blockIdx.x;
  const int lane = threadIdx.x & 63;
  const int wv = threadIdx.x >> 6;
  const int l15 = lane & 15, lq = lane >> 4;

  __shared__ float sred[2][4][64];

  floatx4 zero = {0.f, 0.f, 0.f, 0.f};
  floatx4 acc[4][8];
#pragma unroll
  for (int mt = 0; mt < 4; ++mt)
#pragma unroll
    for (int nt = 0; nt < 8; ++nt) acc[mt][nt] = zero;

  const unsigned short* abase = call + ((size_t)tb * 64 + l15) * 1024 + lq * 8;
  const unsigned short* bbase = wout + ((size_t)(wv * 128 + l15)) * 1024 + lq * 8;

#pragma unroll 2
  for (int ks = 0; ks < 32; ++ks) {
    bf16x8 a[4];
#pragma unroll
    for (int mt = 0; mt < 4; ++mt)
      a[mt] = *(const bf16x8*)(abase + (size_t)mt * 16 * 1024 + ks * 32);
#pragma unroll
    for (int nt = 0; nt < 8; ++nt) {
      const bf16x8 b = *(const bf16x8*)(bbase + (size_t)nt * 16 * 1024 + ks * 32);
#pragma unroll
      for (int mt = 0; mt < 4; ++mt)
        acc[mt][nt] = __builtin_amdgcn_mfma_f32_16x16x32_bf16(a[mt], b, acc[mt][nt], 0, 0, 0);
    }
  }

#pragma unroll
  for (int nt = 0; nt < 8; ++nt) {
    const float bo = bout[wv * 128 + nt * 16 + l15];
#pragma unroll
    for (int mt = 0; mt < 4; ++mt)
#pragma unroll
      for (int r = 0; r < 4; ++r) acc[mt][nt][r] += bo;
  }

  float rmax[4][4];
#pragma unroll
  for (int mt = 0; mt < 4; ++mt)
#pragma unroll
    for (int r = 0; r < 4; ++r) {
      float m = acc[mt][0][r];
#pragma unroll
      for (int nt = 1; nt < 8; ++nt) m = fmaxf(m, acc[mt][nt][r]);
      m = fmaxf(m, __shfl_xor(m, 1, 64));
      m = fmaxf(m, __shfl_xor(m, 2, 64));
      m = fmaxf(m, __shfl_xor(m, 4, 64));
      m = fmaxf(m, __shfl_xor(m, 8, 64));
      rmax[mt][r] = m;
    }
  if (l15 == 0) {
#pragma unroll
    for (int mt = 0; mt < 4; ++mt)
#pragma unroll
      for (int r = 0; r < 4; ++r) sred[0][wv][mt * 16 + lq * 4 + r] = rmax[mt][r];
  }
  __syncthreads();
  float gmax[4][4], rsum[4][4];
#pragma unroll
  for (int mt = 0; mt < 4; ++mt)
#pragma unroll
    for (int r = 0; r < 4; ++r) {
      const int rw = mt * 16 + lq * 4 + r;
      gmax[mt][r] = fmaxf(fmaxf(sred[0][0][rw], sred[0][1][rw]),
                          fmaxf(sred[0][2][rw], sred[0][3][rw]));
      rsum[mt][r] = 0.f;
    }
#pragma unroll
  for (int mt = 0; mt < 4; ++mt)
#pragma unroll
    for (int nt = 0; nt < 8; ++nt)
#pragma unroll
      for (int r = 0; r < 4; ++r) {
        const float e = __expf(acc[mt][nt][r] - gmax[mt][r]);
        acc[mt][nt][r] = e;
        rsum[mt][r] += e;
      }
#pragma unroll
  for (int mt = 0; mt < 4; ++mt)
#pragma unroll
    for (int r = 0; r < 4; ++r) {
      float s = rsum[mt][r];
      s += __shfl_xor(s, 1, 64);
      s += __shfl_xor(s, 2, 64);
      s += __shfl_xor(s, 4, 64);
      s += __shfl_xor(s, 8, 64);
      rsum[mt][r] = s;
    }
  if (l15 == 0) {
#pragma unroll
    for (int mt = 0; mt < 4; ++mt)
#pragma unroll
      for (int r = 0; r < 4; ++r) sred[1][wv][mt * 16 + lq * 4 + r] = rsum[mt][r];
  }
  __syncthreads();
#pragma unroll
  for (int mt = 0; mt < 4; ++mt)
#pragma unroll
    for (int r = 0; r < 4; ++r) {
      const int rw = mt * 16 + lq * 4 + r;
      const float inv = 1.0f / (sred[1][0][rw] + sred[1][1][rw] +
                                sred[1][2][rw] + sred[1][3][rw]);
      float* orow = out + ((size_t)tb * 64 + rw) * 512 + wv * 128 + l15;
#pragma unroll
      for (int nt = 0; nt < 8; ++nt) orow[nt * 16] = acc[mt][nt][r] * inv;
    }
}

// ---------------- launch ----------------
extern "C" void kernel_launch(void* const* d_in, const int* in_sizes, int n_in,
                              void* d_out, int out_size, void* d_ws, size_t ws_size,
                              hipStream_t stream) {
  const float* x    = (const float*)d_in[0];
  const float* Wih  = (const float*)d_in[1];
  const float* Whh  = (const float*)d_in[2];
  const float* bih  = (const float*)d_in[3];
  const float* bhh  = (const float*)d_in[4];
  const float* Wout = (const float*)d_in[5];
  const float* bout = (const float*)d_in[6];
  const float* h0   = (const float*)d_in[7];
  const float* c0   = (const float*)d_in[8];
  float* out = (float*)d_out;

  char* ws = (char*)d_ws;
  unsigned short* hbuf  = (unsigned short*)(ws + 4096);         //   256 KB
  unsigned short* woutb = (unsigned short*)(ws + 266240);       //     1 MB
  unsigned short* xT    = (unsigned short*)(ws + 1314816);      //    16 MB
  unsigned short* call  = (unsigned short*)(ws + 18092032);     //    32 MB

  // poison both h buffers: 0xFFFF has bit14=1, first expected tag is 0 for
  // both buffers (buf0 first polled at t=1 for tag0; buf1 at t=2 for tag0).
  hipMemsetAsync(hbuf, 0xFF, 262144, stream);
  cvt_w<<<256, 256, 0, stream>>>(Wout, woutb);
  transpose_x<<<dim3(8, 16, 64), 256, 0, stream>>>(x, xT);
  lstm_rec<<<256, 512, 0, stream>>>(Whh, Wih, bih, bhh, h0, c0, xT, hbuf, call);
  lstm_head<<<256, 256, 0, stream>>>(call, woutb, bout, out);
}